// Round 1
// baseline (154.290 us; speedup 1.0000x reference)
//
#include <hip/hip_runtime.h>
#include <hip/hip_bf16.h>

#define LL 512
#define HH 128
#define NBATCH 2
#define NT 32   // 512/16 tiles per side

typedef float f32x4 __attribute__((ext_vector_type(4)));
typedef short s16x8 __attribute__((ext_vector_type(8)));
typedef short s16x4 __attribute__((ext_vector_type(4)));

__device__ __forceinline__ short f2bf(float f){
  __hip_bfloat16 h = __float2bfloat16(f);
  return __builtin_bit_cast(short, h);
}
__device__ __forceinline__ float4 max4(float4 a, float4 b){
  return make_float4(fmaxf(a.x,b.x), fmaxf(a.y,b.y), fmaxf(a.z,b.z), fmaxf(a.w,b.w));
}
// exact-enough gelu: tanh form == v * sigmoid(2*0.79788456*(v+0.044715 v^3))
__device__ __forceinline__ float gelu_f(float v){
  float vv = v*v;
  float inner = v * fmaf(0.044715f, vv, 1.0f);
  float e = __expf(1.5957691216f * inner);
  float r = __fdividef(1.0f, e + 1.0f);
  return fmaf(-v, r, v);   // v*(1 - 1/(e+1)) = v*sigmoid(2z)
}

// ---- prep: t1[b,l,g] = x[b,l,:]·W[g,0:128] + bias[g]; t2 = y·W[g,128:256] ----
__global__ void prep_kernel(const float* __restrict__ x, const float* __restrict__ y,
                            const float* __restrict__ W, const float* __restrict__ bias,
                            float* __restrict__ t1, float* __restrict__ t2){
  int l = blockIdx.x, b = blockIdx.y;
  __shared__ float xs[HH], ys[HH];
  int tid = threadIdx.x;
  size_t base = ((size_t)b*LL + l)*HH;
  xs[tid] = x[base + tid];
  ys[tid] = y[base + tid];
  __syncthreads();
  const float4* wr1 = (const float4*)(W + (size_t)tid*384);
  const float4* wr2 = (const float4*)(W + (size_t)tid*384 + 128);
  const float4* xs4 = (const float4*)xs;
  const float4* ys4 = (const float4*)ys;
  float s1 = 0.f, s2 = 0.f;
  #pragma unroll
  for (int q=0;q<32;++q){
    float4 a = xs4[q], w = wr1[q];
    s1 = fmaf(a.x,w.x, fmaf(a.y,w.y, fmaf(a.z,w.z, fmaf(a.w,w.w, s1))));
    float4 c = ys4[q], w2 = wr2[q];
    s2 = fmaf(c.x,w2.x, fmaf(c.y,w2.y, fmaf(c.z,w2.z, fmaf(c.w,w2.w, s2))));
  }
  t1[base + tid] = s1 + bias[tid];
  t2[base + tid] = s2;
}

// ---- misc: bmax[b,t,h] = max over 16 rows; Wcb = bf16(W[:,256:384]) ----
__global__ void misc_kernel(const float* __restrict__ x, const float* __restrict__ W,
                            float* __restrict__ bmax, short* __restrict__ Wcb){
  int blk = blockIdx.x, tid = threadIdx.x;
  if (blk < NBATCH*NT){
    int b = blk >> 5, t = blk & 31;
    float m = -INFINITY;
    #pragma unroll
    for (int r=0;r<16;++r) m = fmaxf(m, x[((size_t)b*LL + t*16 + r)*HH + tid]);
    bmax[(size_t)blk*HH + tid] = m;
  } else {
    int g = blk - NBATCH*NT;
    Wcb[g*HH + tid] = f2bf(W[(size_t)g*384 + 256 + tid]);
  }
}

// ---- main: one block per (i-tile, j-tile, b); 256 pairs × 128 GEMM + epilogue ----
__global__ __launch_bounds__(512) void ctx_kernel(
    const float* __restrict__ x, const float* __restrict__ t1,
    const float* __restrict__ t2, const float* __restrict__ bmax,
    const short* __restrict__ Wcb, float* __restrict__ out)
{
  const int ti = blockIdx.x, tj = blockIdx.y, b = blockIdx.z;
  const int tid = threadIdx.x;
  __shared__ float loR[16][HH];
  __shared__ float hiR[16][HH];
  __shared__ short Atile[256*HH];   // bf16 bits, XOR-swizzled
  const int tlo = min(ti,tj), thi = max(ti,tj);

  // load tile rows (each thread one float4 per tile)
  {
    int row = tid >> 5;
    int q = tid & 31;
    const float4* xs = (const float4*)(x + ((size_t)(b*LL) + tlo*16 + row)*HH);
    ((float4*)loR[row])[q] = xs[q];
    const float4* xs2 = (const float4*)(x + ((size_t)(b*LL) + thi*16 + row)*HH);
    ((float4*)hiR[row])[q] = xs2[q];
  }
  __syncthreads();

  auto storeA = [&](int p, int h, float4 v){
    int e = p*HH + (h ^ ((p&7)<<3));
    s16x4 sv = { f2bf(v.x), f2bf(v.y), f2bf(v.z), f2bf(v.w) };
    *(s16x4*)&Atile[e] = sv;
  };

  if (ti != tj) {
    // in-place scans: loR -> suffix max, hiR -> prefix max
    if (tid < HH) {
      int h = tid;
      for (int r=14; r>=0; --r) loR[r][h] = fmaxf(loR[r][h], loR[r+1][h]);
    } else if (tid < 2*HH) {
      int h = tid - HH;
      for (int r=1; r<16; ++r) hiR[r][h] = fmaxf(hiR[r][h], hiR[r-1][h]);
    }
    __syncthreads();
    int pp = tid >> 5;          // ii (i-row within tile)
    int h = (tid & 31) * 4;
    float4 g4 = make_float4(-INFINITY,-INFINITY,-INFINITY,-INFINITY);
    for (int t = tlo+1; t < thi; ++t){
      float4 bm = *(const float4*)(bmax + ((size_t)(b*NT + t))*HH + h);
      g4 = max4(g4, bm);
    }
    // fixed per-thread part: lo-suffix (if i-tile is lo) else hi-prefix, at row pp
    float4 fixed = max4(g4, (ti < tj) ? *(const float4*)&loR[pp][h]
                                      : *(const float4*)&hiR[pp][h]);
    #pragma unroll
    for (int q=0; q<16; ++q){
      float4 other = (ti < tj) ? *(const float4*)&hiR[q][h]
                               : *(const float4*)&loR[q][h];
      storeA(pp*16 + q, h, max4(fixed, other));
    }
  } else {
    // diagonal tile: per-pair in-tile range max
    int ii = tid >> 5;
    int h = (tid & 31) * 4;
    float4 base = *(const float4*)&loR[ii][h];
    storeA(ii*16 + ii, h, base);
    float4 cur = base;
    for (int jj=ii+1; jj<16; ++jj){
      cur = max4(cur, *(const float4*)&loR[jj][h]);
      storeA(ii*16 + jj, h, cur);
    }
    cur = base;
    for (int jj=ii-1; jj>=0; --jj){
      cur = max4(cur, *(const float4*)&loR[jj][h]);
      storeA(ii*16 + jj, h, cur);
    }
  }
  __syncthreads();

  // GEMM: A[256x128] (LDS bf16) × Wc^T[128x128] (global bf16) -> 256x128 f32
  const int w = tid >> 6;          // wave 0..7
  const int l = tid & 63;
  const int lane16 = l & 15, lhi = l >> 4;

  f32x4 acc[2][8];
  #pragma unroll
  for (int mt=0; mt<2; ++mt)
    #pragma unroll
    for (int nt=0; nt<8; ++nt)
      acc[mt][nt] = (f32x4){0.f,0.f,0.f,0.f};

  s16x8 afrag[2][4];
  #pragma unroll
  for (int mt=0; mt<2; ++mt){
    int p = (w*2+mt)*16 + lane16;
    #pragma unroll
    for (int kb=0; kb<4; ++kb){
      int hh2 = kb*32 + lhi*8;
      int e = p*HH + (hh2 ^ ((p&7)<<3));
      afrag[mt][kb] = *(const s16x8*)&Atile[e];
    }
  }
  #pragma unroll
  for (int nt=0; nt<8; ++nt){
    int g = nt*16 + lane16;
    s16x8 bfrag[4];
    #pragma unroll
    for (int kb=0; kb<4; ++kb){
      int k = kb*32 + lhi*8;
      bfrag[kb] = *(const s16x8*)(Wcb + g*HH + k);
    }
    #pragma unroll
    for (int mt=0; mt<2; ++mt)
      #pragma unroll
      for (int kb=0; kb<4; ++kb)
        acc[mt][nt] = __builtin_amdgcn_mfma_f32_16x16x32_bf16(afrag[mt][kb], bfrag[kb], acc[mt][nt], 0, 0, 0);
  }

  // epilogue: + t1[b,i,g] + t2[b,j,g], gelu, store
  const int i0 = ti*16, j0 = tj*16;
  #pragma unroll
  for (int mt=0; mt<2; ++mt){
    int mtg = w*2 + mt;
    #pragma unroll
    for (int nt=0; nt<8; ++nt){
      int g = nt*16 + lane16;
      #pragma unroll
      for (int jr=0; jr<4; ++jr){
        int p = mtg*16 + lhi*4 + jr;
        int ii = p >> 4, jj = p & 15;
        float v = acc[mt][nt][jr]
                + t1[((size_t)(b*LL) + i0+ii)*HH + g]
                + t2[((size_t)(b*LL) + j0+jj)*HH + g];
        out[(((size_t)(b*LL) + i0+ii)*LL + (j0+jj))*HH + g] = gelu_f(v);
      }
    }
  }
}

extern "C" void kernel_launch(void* const* d_in, const int* in_sizes, int n_in,
                              void* d_out, int out_size, void* d_ws, size_t ws_size,
                              hipStream_t stream) {
  const float* x    = (const float*)d_in[0];
  const float* y    = (const float*)d_in[1];
  const float* W    = (const float*)d_in[2];
  const float* bias = (const float*)d_in[3];
  float* out = (float*)d_out;

  float* t1 = (float*)d_ws;                       // B*L*H
  float* t2 = t1 + (size_t)NBATCH*LL*HH;          // B*L*H
  float* bmax = t2 + (size_t)NBATCH*LL*HH;        // B*32*H
  short* Wcb = (short*)(bmax + (size_t)NBATCH*NT*HH); // 128*128 bf16

  prep_kernel<<<dim3(LL, NBATCH), 128, 0, stream>>>(x, y, W, bias, t1, t2);
  misc_kernel<<<NBATCH*NT + HH, HH, 0, stream>>>(x, W, bmax, Wcb);
  ctx_kernel<<<dim3(NT, NT, NBATCH), 512, 0, stream>>>(x, t1, t2, bmax, Wcb, out);
}

// Round 2
// 98.879 us; speedup vs baseline: 1.5604x; 1.5604x over previous
//
#include <hip/hip_runtime.h>
#include <hip/hip_bf16.h>

#define LL 512
#define HH 128
#define NBATCH 2
#define NT 32                 // 512/16 tiles per side
#define NPAIR (NT*(NT+1)/2)   // 528 unordered tile pairs

typedef float f32x4 __attribute__((ext_vector_type(4)));
typedef short s16x8 __attribute__((ext_vector_type(8)));
typedef short s16x4 __attribute__((ext_vector_type(4)));

__device__ __forceinline__ unsigned short f2bfu(float f){
  __hip_bfloat16 h = __float2bfloat16(f);
  return __builtin_bit_cast(unsigned short, h);
}
__device__ __forceinline__ short f2bf(float f){
  __hip_bfloat16 h = __float2bfloat16(f);
  return __builtin_bit_cast(short, h);
}
__device__ __forceinline__ f32x4 max4v(f32x4 a, f32x4 b){
  f32x4 r; r[0]=fmaxf(a[0],b[0]); r[1]=fmaxf(a[1],b[1]);
  r[2]=fmaxf(a[2],b[2]); r[3]=fmaxf(a[3],b[3]); return r;
}
// gelu via v*sigmoid(2*0.79788456*(v+0.044715 v^3)) — matches exact erf gelu to ~3e-3
__device__ __forceinline__ float gelu_f(float v){
  float inner = v * fmaf(0.044715f, v*v, 1.0f);
  float e = __expf(1.5957691216f * inner);
  float s = __fdividef(1.0f, e + 1.0f);
  return fmaf(-v, s, v);
}
__device__ __forceinline__ f32x4 gelu4(f32x4 v){
  f32x4 r;
  #pragma unroll
  for (int i=0;i<4;++i) r[i] = gelu_f(v[i]);
  return r;
}

// ---- prep: t1[b,l,g] = x[b,l,:]·W[:,g] + bias[g]; t2 = y·W[:,128+g] ----
__global__ void prep_kernel(const float* __restrict__ x, const float* __restrict__ y,
                            const float* __restrict__ W, const float* __restrict__ bias,
                            float* __restrict__ t1, float* __restrict__ t2){
  int l = blockIdx.x, b = blockIdx.y;
  __shared__ float xs[HH], ys[HH];
  int tid = threadIdx.x;
  size_t base = ((size_t)b*LL + l)*HH;
  xs[tid] = x[base + tid];
  ys[tid] = y[base + tid];
  __syncthreads();
  const float4* wr1 = (const float4*)(W + (size_t)tid*384);
  const float4* wr2 = (const float4*)(W + (size_t)tid*384 + 128);
  const float4* xs4 = (const float4*)xs;
  const float4* ys4 = (const float4*)ys;
  float s1 = 0.f, s2 = 0.f;
  #pragma unroll
  for (int q=0;q<32;++q){
    float4 a = xs4[q], w = wr1[q];
    s1 = fmaf(a.x,w.x, fmaf(a.y,w.y, fmaf(a.z,w.z, fmaf(a.w,w.w, s1))));
    float4 c = ys4[q], w2 = wr2[q];
    s2 = fmaf(c.x,w2.x, fmaf(c.y,w2.y, fmaf(c.z,w2.z, fmaf(c.w,w2.w, s2))));
  }
  t1[base + tid] = s1 + bias[tid];
  t2[base + tid] = s2;
}

// ---- misc: bmax[b,t,h] = max over 16 rows of x; Wcb = bf16(W[:,256:384]) g-major ----
__global__ void misc_kernel(const float* __restrict__ x, const float* __restrict__ W,
                            float* __restrict__ bmax, short* __restrict__ Wcb){
  int blk = blockIdx.x, tid = threadIdx.x;
  if (blk < NBATCH*NT){
    int b = blk >> 5, t = blk & 31;
    float m = -INFINITY;
    #pragma unroll
    for (int r=0;r<16;++r) m = fmaxf(m, x[((size_t)b*LL + t*16 + r)*HH + tid]);
    bmax[(size_t)blk*HH + tid] = m;
  } else {
    int g = blk - NBATCH*NT;
    Wcb[g*HH + tid] = f2bf(W[(size_t)g*384 + 256 + tid]);
  }
}

// ---- main: one block per unordered tile pair (ti<=tj) per batch ----
__global__ __launch_bounds__(512, 4) void ctx_kernel(
    const float* __restrict__ x, const float* __restrict__ t1,
    const float* __restrict__ t2, const float* __restrict__ bmax,
    const short* __restrict__ Wcb, float* __restrict__ out)
{
  __shared__ unsigned short sfxS[16][HH];   // suffix-max of ti-tile rows (bf16 bits)
  __shared__ unsigned short pfxS[16][HH];   // prefix-max of tj-tile rows
  __shared__ float gmaxS[HH];               // max over strictly-between tiles
  __shared__ unsigned short Atile[256*HH];  // ctx pairs, bf16, XOR-swizzled

  const int tid = threadIdx.x;
  const int b = blockIdx.y;
  // decode unordered pair index -> (ti, tj), ti <= tj
  int ti = 0, tj;
  { int rem = blockIdx.x;
    while (rem >= NT - ti){ rem -= NT - ti; ++ti; }
    tj = ti + rem; }

  // ---- phase A (off-diag only): column scans + gap max into LDS ----
  if (ti != tj && tid < 3*HH) {
    int role = tid >> 7;        // 0: sfx(ti), 1: pfx(tj), 2: gap
    int h = tid & (HH-1);
    if (role == 0){
      const float* xp = x + ((size_t)b*LL + ti*16)*HH + h;
      float v[16];
      #pragma unroll
      for (int r=0;r<16;++r) v[r] = xp[(size_t)r*HH];
      float run = -INFINITY;
      #pragma unroll
      for (int r=15;r>=0;--r){ run = fmaxf(run, v[r]); sfxS[r][h] = f2bfu(run); }
    } else if (role == 1){
      const float* xp = x + ((size_t)b*LL + tj*16)*HH + h;
      float v[16];
      #pragma unroll
      for (int r=0;r<16;++r) v[r] = xp[(size_t)r*HH];
      float run = -INFINITY;
      #pragma unroll
      for (int r=0;r<16;++r){ run = fmaxf(run, v[r]); pfxS[r][h] = f2bfu(run); }
    } else {
      float g = -INFINITY;
      for (int t = ti+1; t < tj; ++t)
        g = fmaxf(g, bmax[((size_t)b*NT + t)*HH + h]);
      gmaxS[h] = g;
    }
  }
  __syncthreads();

  // ---- phase B: build Atile[p = ii*16 + q][h] = ctx(i0+ii, j0+q, h) in bf16 ----
  {
    const int grp = tid >> 5;           // 0..15
    const int hq  = (tid & 31) * 4;
    auto storeA = [&](int p, f32x4 v){
      int e = p*HH + (hq ^ ((p&7)<<3));
      s16x4 sv = { f2bf(v[0]), f2bf(v[1]), f2bf(v[2]), f2bf(v[3]) };
      *(s16x4*)&Atile[e] = sv;
    };
    auto unpk4 = [&](const unsigned short* pp)->f32x4{
      uint2 u = *(const uint2*)pp;
      f32x4 r;
      r[0] = __uint_as_float(u.x << 16);
      r[1] = __uint_as_float(u.x & 0xFFFF0000u);
      r[2] = __uint_as_float(u.y << 16);
      r[3] = __uint_as_float(u.y & 0xFFFF0000u);
      return r;
    };
    if (ti != tj){
      f32x4 fx = *(const f32x4*)&gmaxS[hq];
      fx = max4v(fx, unpk4(&sfxS[grp][hq]));
      #pragma unroll
      for (int q=0;q<16;++q){
        f32x4 v = max4v(fx, unpk4(&pfxS[q][hq]));
        storeA(grp*16 + q, v);
      }
    } else {
      const float* xbase = x + ((size_t)b*LL + ti*16)*HH + hq;
      f32x4 base = *(const f32x4*)(xbase + (size_t)grp*HH);
      storeA(grp*16 + grp, base);
      f32x4 cur = base;
      for (int q=grp+1;q<16;++q){
        cur = max4v(cur, *(const f32x4*)(xbase + (size_t)q*HH));
        storeA(grp*16 + q, cur);
      }
      cur = base;
      for (int q=grp-1;q>=0;--q){
        cur = max4v(cur, *(const f32x4*)(xbase + (size_t)q*HH));
        storeA(grp*16 + q, cur);
      }
    }
  }
  __syncthreads();

  // ---- phase C: D[g,p] = Wc·A^T via MFMA (A-op = Wc so g lands in regs), fused epilogue ----
  const int w   = tid >> 6;       // wave = g-tile 0..7
  const int l   = tid & 63;
  const int l16 = l & 15, lhi = l >> 4;

  s16x8 wcf[4];
  #pragma unroll
  for (int kb=0;kb<4;++kb)
    wcf[kb] = *(const s16x8*)(Wcb + (size_t)(w*16 + l16)*HH + kb*32 + lhi*8);

  const int g0 = w*16 + lhi*4;
  const int swz = (l16 & 7) << 3;
  const int qrow = tj*16 + l16;
  const size_t t_qoff = ((size_t)b*LL + qrow)*HH + g0;
  const bool offd = (ti != tj);

  #pragma unroll
  for (int pt=0; pt<16; ++pt){
    const int p = pt*16 + l16;
    f32x4 acc = (f32x4){0.f,0.f,0.f,0.f};
    #pragma unroll
    for (int kb=0;kb<4;++kb){
      int hh2 = (kb*32 + lhi*8) ^ swz;
      s16x8 bf8 = *(const s16x8*)&Atile[p*HH + hh2];
      acc = __builtin_amdgcn_mfma_f32_16x16x32_bf16(wcf[kb], bf8, acc, 0, 0, 0);
    }
    const int irow = ti*16 + pt;               // uniform per pt
    const size_t t_ioff = ((size_t)b*LL + irow)*HH + g0;
    // out1: (i from ti-tile row pt, j from tj-tile row l16)
    f32x4 t1i = *(const f32x4*)(t1 + t_ioff);
    f32x4 t2j = *(const f32x4*)(t2 + t_qoff);
    f32x4 o1 = gelu4(acc + t1i + t2j);
    *(f32x4*)(out + ((size_t)(b*LL + irow)*LL + qrow)*HH + g0) = o1;
    if (offd){
      // out2: (i from tj-tile row l16, j from ti-tile row pt)
      f32x4 t1j = *(const f32x4*)(t1 + t_qoff);
      f32x4 t2i = *(const f32x4*)(t2 + t_ioff);
      f32x4 o2 = gelu4(acc + t1j + t2i);
      *(f32x4*)(out + ((size_t)(b*LL + qrow)*LL + irow)*HH + g0) = o2;
    }
  }
}

extern "C" void kernel_launch(void* const* d_in, const int* in_sizes, int n_in,
                              void* d_out, int out_size, void* d_ws, size_t ws_size,
                              hipStream_t stream) {
  const float* x    = (const float*)d_in[0];
  const float* y    = (const float*)d_in[1];
  const float* W    = (const float*)d_in[2];
  const float* bias = (const float*)d_in[3];
  float* out = (float*)d_out;

  float* t1 = (float*)d_ws;                           // B*L*H f32
  float* t2 = t1 + (size_t)NBATCH*LL*HH;              // B*L*H f32
  float* bmax = t2 + (size_t)NBATCH*LL*HH;            // B*NT*H f32
  short* Wcb = (short*)(bmax + (size_t)NBATCH*NT*HH); // 128*128 bf16

  prep_kernel<<<dim3(LL, NBATCH), HH, 0, stream>>>(x, y, W, bias, t1, t2);
  misc_kernel<<<NBATCH*NT + HH, HH, 0, stream>>>(x, W, bmax, Wcb);
  ctx_kernel<<<dim3(NPAIR, NBATCH), 512, 0, stream>>>(x, t1, t2, bmax, Wcb, out);
}